// Round 2
// baseline (746.044 us; speedup 1.0000x reference)
//
#include <hip/hip_runtime.h>
#include <hip/hip_bf16.h>
#include <stdint.h>

typedef uint16_t u16;
typedef __bf16 bf16x8 __attribute__((ext_vector_type(8)));
typedef float f32x4 __attribute__((ext_vector_type(4)));
typedef u16 u16x4 __attribute__((ext_vector_type(4)));

#define S_LEN 2048
#define D_MODEL 4096
#define N_HEADS 32
#define N_KVH 8
#define HEAD_DIM 128
#define QD 4096   // N_HEADS*HEAD_DIM
#define KVD 1024  // N_KVH*HEAD_DIM

__device__ __forceinline__ float bf2f(u16 x) {
    union { unsigned u; float f; } c; c.u = ((unsigned)x) << 16; return c.f;
}
__device__ __forceinline__ u16 f2bf(float f) {
    union { float f; unsigned u; } c; c.f = f;
    unsigned u = c.u;
    u += 0x7fffu + ((u >> 16) & 1u);
    return (u16)(u >> 16);
}

// ---------------- f32 -> bf16 convert (vectorized x4) ----------------
__global__ __launch_bounds__(256) void conv_f2b_kernel(
    const float* __restrict__ in, u16* __restrict__ out, int n4)
{
    int i = blockIdx.x * blockDim.x + threadIdx.x;
    if (i < n4) {
        float4 v = ((const float4*)in)[i];
        u16x4 o;
        o.x = f2bf(v.x); o.y = f2bf(v.y); o.z = f2bf(v.z); o.w = f2bf(v.w);
        ((u16x4*)out)[i] = o;
    }
}

// ---------------- transpose+convert: in f32 (R,C) -> out bf16 (C,R) ----------------
__global__ __launch_bounds__(256) void transpose_f2b_kernel(
    const float* __restrict__ in, u16* __restrict__ out, int R, int C)
{
    __shared__ u16 tile[32][33];
    const int cb = blockIdx.x * 32;
    const int rb = blockIdx.y * 32;
    const int tx = threadIdx.x;       // 0..31
    const int ty0 = threadIdx.y;      // 0..7
#pragma unroll
    for (int i = 0; i < 4; ++i) {
        int ty = ty0 + i * 8;
        tile[ty][tx] = f2bf(in[(size_t)(rb + ty) * C + cb + tx]);
    }
    __syncthreads();
#pragma unroll
    for (int i = 0; i < 4; ++i) {
        int ty = ty0 + i * 8;
        out[(size_t)(cb + ty) * R + rb + tx] = tile[tx][ty];
    }
}

// ---------------- transpose bf16 (R,C) -> (C,R) ----------------
__global__ __launch_bounds__(256) void transpose_kernel(
    const u16* __restrict__ in, u16* __restrict__ out, int R, int C)
{
    __shared__ u16 tile[32][33];
    const int cb = blockIdx.x * 32;
    const int rb = blockIdx.y * 32;
    const int tx = threadIdx.x;
    const int ty0 = threadIdx.y;
#pragma unroll
    for (int i = 0; i < 4; ++i) {
        int ty = ty0 + i * 8;
        tile[ty][tx] = in[(size_t)(rb + ty) * C + cb + tx];
    }
    __syncthreads();
#pragma unroll
    for (int i = 0; i < 4; ++i) {
        int ty = ty0 + i * 8;
        out[(size_t)(cb + ty) * R + rb + tx] = tile[tx][ty];
    }
}

// ---------------- GEMM: C(M,N) = A(M,K) @ BT(N,K)^T, bf16 in, fp32 acc ----------------
#define BM 128
#define BN 128
#define BKK 64

template <typename OT>
__global__ __launch_bounds__(256) void gemm_bt_kernel(
    const u16* __restrict__ A, const u16* __restrict__ BT, OT* __restrict__ C,
    int M, int N, int K)
{
    __shared__ u16 sA[BM * BKK];
    __shared__ u16 sB[BN * BKK];
    const int nbx = N / BN;
    const int bx = blockIdx.x % nbx;
    const int by = blockIdx.x / nbx;
    const int row0 = by * BM, col0 = bx * BN;
    const int t = threadIdx.x;
    const int w = t >> 6, l = t & 63;
    const int wr = w >> 1, wc = w & 1;
    const int l16 = l & 15, lk = l >> 4;

    f32x4 acc[4][4] = {};

    for (int k0 = 0; k0 < K; k0 += BKK) {
        bf16x8 ra[4], rb[4];
#pragma unroll
        for (int j = 0; j < 4; ++j) {
            int flat = j * 256 + t;   // 16B chunk id within the 128x64 tile
            int r = flat >> 3;        // tile row
            int cch = flat & 7;       // 16B chunk within row
            ra[j] = *(const bf16x8*)(A  + (size_t)(row0 + r) * K + k0 + cch * 8);
            rb[j] = *(const bf16x8*)(BT + (size_t)(col0 + r) * K + k0 + cch * 8);
        }
        __syncthreads();
#pragma unroll
        for (int j = 0; j < 4; ++j) {
            int flat = j * 256 + t;
            int r = flat >> 3;
            int cch = flat & 7;
            int sc = cch ^ (r & 7);   // XOR swizzle (16B granules)
            *(bf16x8*)(sA + r * BKK + sc * 8) = ra[j];
            *(bf16x8*)(sB + r * BKK + sc * 8) = rb[j];
        }
        __syncthreads();
#pragma unroll
        for (int kk = 0; kk < 2; ++kk) {
            bf16x8 af[4], bfr[4];
#pragma unroll
            for (int m = 0; m < 4; ++m) {
                int r = wr * 64 + m * 16 + l16;
                int ch = (kk * 4 + lk) ^ (r & 7);
                af[m] = *(const bf16x8*)(sA + r * BKK + ch * 8);
            }
#pragma unroll
            for (int n = 0; n < 4; ++n) {
                int r = wc * 64 + n * 16 + l16;
                int ch = (kk * 4 + lk) ^ (r & 7);
                bfr[n] = *(const bf16x8*)(sB + r * BKK + ch * 8);
            }
#pragma unroll
            for (int m = 0; m < 4; ++m)
#pragma unroll
                for (int n = 0; n < 4; ++n)
                    acc[m][n] = __builtin_amdgcn_mfma_f32_16x16x32_bf16(
                        af[m], bfr[n], acc[m][n], 0, 0, 0);
        }
    }
#pragma unroll
    for (int m = 0; m < 4; ++m)
#pragma unroll
        for (int n = 0; n < 4; ++n)
#pragma unroll
            for (int j = 0; j < 4; ++j) {
                int row = row0 + wr * 64 + m * 16 + lk * 4 + j;
                int col = col0 + wc * 64 + n * 16 + l16;
                if constexpr (sizeof(OT) == 2)
                    C[(size_t)row * N + col] = f2bf(acc[m][n][j]);
                else
                    C[(size_t)row * N + col] = acc[m][n][j];
            }
}

// ---------------- RoPE cos/sin table: (S,64) fp32 each ----------------
__global__ void rope_table_kernel(const int* __restrict__ pos,
                                  float* __restrict__ ctab, float* __restrict__ stab)
{
    int s = blockIdx.x;
    int i = threadIdx.x; // 0..63
    float p = (float)pos[s];
    float freq = __expf(-(float)i * (9.210340371976184f / 64.0f)); // 10000^(-i/64)
    float ang = p * freq;
    ctab[s * 64 + i] = cosf(ang);
    stab[s * 64 + i] = sinf(ang);
}

// ---------------- RoPE apply (in place, bf16). block = nheads*32 threads ----------------
__global__ void rope_apply_kernel(u16* __restrict__ X,
                                  const float* __restrict__ ctab, const float* __restrict__ stab,
                                  int nheads)
{
    int s = blockIdx.x;
    int t = threadIdx.x;
    int head = t >> 5;
    int j = t & 31;
    size_t base = (size_t)s * (nheads * 128) + head * 128;
    float x1 = bf2f(X[base + j]);
    float x2 = bf2f(X[base + j + 32]);
    float c1 = ctab[s * 64 + j],      s1 = stab[s * 64 + j];
    float c2 = ctab[s * 64 + j + 32], s2 = stab[s * 64 + j + 32];
    X[base + j]      = f2bf(x1 * c1 - x2 * s1);
    X[base + j + 32] = f2bf(x2 * c2 + x1 * s2);
}

// ---------------- flash attention: 1 wave per (16-row q block, head) ----------------
__global__ __launch_bounds__(64) void attn_kernel(
    const u16* __restrict__ Q, const u16* __restrict__ Km, const u16* __restrict__ VT,
    u16* __restrict__ AO)
{
    const int qb = blockIdx.x;
    const int h  = blockIdx.y;
    const int hkv = h >> 2;
    const int q0 = qb * 16;
    const int l = threadIdx.x;
    const int l16 = l & 15, lk = l >> 4;
    __shared__ u16 sP[16 * 32];

    bf16x8 qf[4];
#pragma unroll
    for (int kk = 0; kk < 4; ++kk)
        qf[kk] = *(const bf16x8*)(Q + (size_t)(q0 + l16) * QD + h * 128 + kk * 32 + lk * 8);

    f32x4 o[8] = {};
    float mrow[4], lrow[4];
#pragma unroll
    for (int j = 0; j < 4; ++j) { mrow[j] = -1e30f; lrow[j] = 0.f; }

    const float scale = 0.08838834764831845f; // 1/sqrt(128)
    const int ntiles = (q0 + 16 + 31) / 32;
    for (int it = 0; it < ntiles; ++it) {
        const int kv0 = it * 32;
        f32x4 sc[2] = {};
#pragma unroll
        for (int c = 0; c < 2; ++c)
#pragma unroll
            for (int kk = 0; kk < 4; ++kk) {
                bf16x8 kf = *(const bf16x8*)(Km + (size_t)(kv0 + c * 16 + l16) * KVD
                                             + hkv * 128 + kk * 32 + lk * 8);
                sc[c] = __builtin_amdgcn_mfma_f32_16x16x32_bf16(qf[kk], kf, sc[c], 0, 0, 0);
            }
        float p[2][4];
        float mx[4];
#pragma unroll
        for (int j = 0; j < 4; ++j) mx[j] = -1e30f;
#pragma unroll
        for (int c = 0; c < 2; ++c)
#pragma unroll
            for (int j = 0; j < 4; ++j) {
                int qrow = q0 + lk * 4 + j;
                int kv = kv0 + c * 16 + l16;
                float v = sc[c][j] * scale;
                if (kv > qrow) v = -1e30f;
                p[c][j] = v;
                mx[j] = fmaxf(mx[j], v);
            }
#pragma unroll
        for (int d = 1; d < 16; d <<= 1)
#pragma unroll
            for (int j = 0; j < 4; ++j)
                mx[j] = fmaxf(mx[j], __shfl_xor(mx[j], d));
        float alpha[4];
#pragma unroll
        for (int j = 0; j < 4; ++j) {
            float mn = fmaxf(mrow[j], mx[j]);
            alpha[j] = __expf(mrow[j] - mn);
            mrow[j] = mn;
        }
        float rs[4];
#pragma unroll
        for (int j = 0; j < 4; ++j) {
            float p0 = __expf(p[0][j] - mrow[j]);
            float p1 = __expf(p[1][j] - mrow[j]);
            p[0][j] = p0; p[1][j] = p1;
            rs[j] = p0 + p1;
        }
#pragma unroll
        for (int d = 1; d < 16; d <<= 1)
#pragma unroll
            for (int j = 0; j < 4; ++j)
                rs[j] += __shfl_xor(rs[j], d);
#pragma unroll
        for (int j = 0; j < 4; ++j)
            lrow[j] = lrow[j] * alpha[j] + rs[j];

        __syncthreads();   // previous PV reads of sP done
#pragma unroll
        for (int c = 0; c < 2; ++c)
#pragma unroll
            for (int j = 0; j < 4; ++j)
                sP[(lk * 4 + j) * 32 + c * 16 + l16] = f2bf(p[c][j]);
        __syncthreads();   // sP visible
        bf16x8 pf = *(const bf16x8*)(sP + l16 * 32 + lk * 8);
#pragma unroll
        for (int n = 0; n < 8; ++n) {
#pragma unroll
            for (int j = 0; j < 4; ++j) o[n][j] *= alpha[j];
            bf16x8 vf = *(const bf16x8*)(VT + (size_t)(hkv * 128 + n * 16 + l16) * S_LEN
                                         + kv0 + lk * 8);
            o[n] = __builtin_amdgcn_mfma_f32_16x16x32_bf16(pf, vf, o[n], 0, 0, 0);
        }
    }
#pragma unroll
    for (int n = 0; n < 8; ++n)
#pragma unroll
        for (int j = 0; j < 4; ++j) {
            int row = q0 + lk * 4 + j;
            int col = h * 128 + n * 16 + l16;
            AO[(size_t)row * QD + col] = f2bf(o[n][j] / lrow[j]);
        }
}

// ---------------- launch ----------------
extern "C" void kernel_launch(void* const* d_in, const int* in_sizes, int n_in,
                              void* d_out, int out_size, void* d_ws, size_t ws_size,
                              hipStream_t stream) {
    const float* X   = (const float*)d_in[0];     // (S, D) fp32
    const int*   pos = (const int*)d_in[2];       // (1, S) int32
    const float* Wq  = (const float*)d_in[3];     // (D, QD) fp32
    const float* Wk  = (const float*)d_in[4];     // (D, KVD) fp32
    const float* Wv  = (const float*)d_in[5];     // (D, KVD) fp32
    const float* Wo  = (const float*)d_in[6];     // (QD, D) fp32
    float* out = (float*)d_out;                   // (S, D) fp32

    char* ws = (char*)d_ws;
    size_t off = 0;
    auto alloc = [&](size_t bytes) -> void* {
        void* p = ws + off;
        off += (bytes + 255) & ~(size_t)255;
        return p;
    };
    u16* Xb  = (u16*)alloc((size_t)S_LEN * D_MODEL * 2);
    u16* WqT = (u16*)alloc((size_t)D_MODEL * QD * 2);
    u16* WkT = (u16*)alloc((size_t)D_MODEL * KVD * 2);
    u16* WvT = (u16*)alloc((size_t)D_MODEL * KVD * 2);
    u16* WoT = (u16*)alloc((size_t)QD * D_MODEL * 2);
    u16* Qm  = (u16*)alloc((size_t)S_LEN * QD * 2);
    u16* Km  = (u16*)alloc((size_t)S_LEN * KVD * 2);
    u16* Vm  = (u16*)alloc((size_t)S_LEN * KVD * 2);
    u16* VTm = (u16*)alloc((size_t)KVD * S_LEN * 2);
    u16* AO  = (u16*)alloc((size_t)S_LEN * QD * 2);
    float* ctab = (float*)alloc((size_t)S_LEN * 64 * 4);
    float* stab = (float*)alloc((size_t)S_LEN * 64 * 4);

    // X -> bf16
    {
        int n4 = (S_LEN * D_MODEL) / 4;
        conv_f2b_kernel<<<dim3((n4 + 255) / 256), dim3(256), 0, stream>>>(X, Xb, n4);
    }

    dim3 tb(32, 8);
    // W (K,N) f32 -> WT (N,K) bf16
    transpose_f2b_kernel<<<dim3(QD / 32, D_MODEL / 32), tb, 0, stream>>>(Wq, WqT, D_MODEL, QD);
    transpose_f2b_kernel<<<dim3(KVD / 32, D_MODEL / 32), tb, 0, stream>>>(Wk, WkT, D_MODEL, KVD);
    transpose_f2b_kernel<<<dim3(KVD / 32, D_MODEL / 32), tb, 0, stream>>>(Wv, WvT, D_MODEL, KVD);
    transpose_f2b_kernel<<<dim3(D_MODEL / 32, QD / 32), tb, 0, stream>>>(Wo, WoT, QD, D_MODEL);

    gemm_bt_kernel<u16><<<dim3((S_LEN / BM) * (QD / BN)), dim3(256), 0, stream>>>(
        Xb, WqT, Qm, S_LEN, QD, D_MODEL);
    gemm_bt_kernel<u16><<<dim3((S_LEN / BM) * (KVD / BN)), dim3(256), 0, stream>>>(
        Xb, WkT, Km, S_LEN, KVD, D_MODEL);
    gemm_bt_kernel<u16><<<dim3((S_LEN / BM) * (KVD / BN)), dim3(256), 0, stream>>>(
        Xb, WvT, Vm, S_LEN, KVD, D_MODEL);

    rope_table_kernel<<<dim3(S_LEN), dim3(64), 0, stream>>>(pos, ctab, stab);
    rope_apply_kernel<<<dim3(S_LEN), dim3(N_HEADS * 32), 0, stream>>>(Qm, ctab, stab, N_HEADS);
    rope_apply_kernel<<<dim3(S_LEN), dim3(N_KVH * 32), 0, stream>>>(Km, ctab, stab, N_KVH);

    transpose_kernel<<<dim3(KVD / 32, S_LEN / 32), tb, 0, stream>>>(Vm, VTm, S_LEN, KVD);

    attn_kernel<<<dim3(S_LEN / 16, N_HEADS), dim3(64), 0, stream>>>(Qm, Km, VTm, AO);

    gemm_bt_kernel<float><<<dim3((S_LEN / BM) * (QD / BN)), dim3(256), 0, stream>>>(
        AO, WoT, out, S_LEN, QD, D_MODEL);
}